// Round 3
// baseline (336.093 us; speedup 1.0000x reference)
//
#include <hip/hip_runtime.h>
#include <type_traits>

#define D_MODEL 1024
#define NHEADS 16
#define DHEAD 64
#define SEQ 2048
#define BATCH 2
#define MROWS (BATCH*SEQ)   // 4096

typedef unsigned short ushort_t;
using bf16x8 = __attribute__((ext_vector_type(8))) __bf16;
using us4    = __attribute__((ext_vector_type(4))) unsigned short;
using us8    = __attribute__((ext_vector_type(8))) unsigned short;
using f32x4  = __attribute__((ext_vector_type(4))) float;

__device__ __forceinline__ ushort_t f2bf(float f) {
    unsigned int u = __builtin_bit_cast(unsigned int, f);
    u += 0x7FFFu + ((u >> 16) & 1u);
    return (ushort_t)(u >> 16);
}

// ---------------------------------------------------------------------------
// Convert fp32 inputs -> canonical bf16: x (4M) + Wq/Wk/Wv/Wo (1M each) = 8M.
// ---------------------------------------------------------------------------
__global__ __launch_bounds__(256) void cvt_kernel(
    const float* __restrict__ x,
    const float* __restrict__ wq, const float* __restrict__ wk,
    const float* __restrict__ wv, const float* __restrict__ wo,
    ushort_t* __restrict__ xb,
    ushort_t* __restrict__ wqb, ushort_t* __restrict__ wkb,
    ushort_t* __restrict__ wvb, ushort_t* __restrict__ wob)
{
    const size_t XN = (size_t)MROWS * D_MODEL;          // 4 Mi
    const size_t WN = (size_t)D_MODEL * D_MODEL;        // 1 Mi
    size_t i = ((size_t)blockIdx.x * 256 + threadIdx.x) * 4;
    const float* s; ushort_t* d; size_t off;
    if (i < XN) { s = x; d = xb; off = i; }
    else {
        size_t j = i - XN;
        int w = (int)(j / WN);
        off = j - (size_t)w * WN;
        s = (w == 0) ? wq : (w == 1) ? wk : (w == 2) ? wv : wo;
        d = (w == 0) ? wqb : (w == 1) ? wkb : (w == 2) ? wvb : wob;
    }
    const f32x4 v = *(const f32x4*)(s + off);
    us4 o;
    #pragma unroll
    for (int t = 0; t < 4; ++t) o[t] = f2bf(v[t]);
    *(us4*)(d + off) = o;
}

// ---------------------------------------------------------------------------
// NT GEMM: Y[M,1024] = A[M,1024] @ W[1024,1024]^T + bias (+ residual, fp32)
// 64x64 tile per block, 4 waves (2x2), each wave 32x32 via 2x2 mfma 16x16x32.
// grid.z selects among 3 weight sets (QKV fused launch).
// ---------------------------------------------------------------------------
template<typename OutT, bool RES>
__global__ __launch_bounds__(256) void gemm_nt(
    const ushort_t* __restrict__ A,
    const ushort_t* __restrict__ W0, const ushort_t* __restrict__ W1, const ushort_t* __restrict__ W2,
    const float* __restrict__ b0, const float* __restrict__ b1, const float* __restrict__ b2,
    const float* __restrict__ res,
    OutT* __restrict__ Y0, OutT* __restrict__ Y1, OutT* __restrict__ Y2)
{
    constexpr int K  = D_MODEL;
    constexpr int BK = 32;
    constexpr int LDP = BK + 8;   // pad: 40 bf16 = 80B rows, keeps 16B alignment
    __shared__ ushort_t As[64 * LDP];
    __shared__ ushort_t Ws[64 * LDP];

    const int z = blockIdx.z;
    const ushort_t* W  = (z == 0) ? W0 : (z == 1) ? W1 : W2;
    const float* bias  = (z == 0) ? b0 : (z == 1) ? b1 : b2;
    OutT* Y            = (z == 0) ? Y0 : (z == 1) ? Y1 : Y2;

    const int i0 = blockIdx.x * 64;
    const int j0 = blockIdx.y * 64;
    const int tid  = threadIdx.x;
    const int lane = tid & 63;
    const int w    = tid >> 6;
    const int wm   = (w >> 1) * 32;
    const int wn   = (w & 1) * 32;
    const int l15  = lane & 15;
    const int quad = lane >> 4;

    const int sr = tid >> 2;          // staging row 0..63
    const int sc = (tid & 3) * 8;     // staging col 0,8,16,24
    const ushort_t* gA = A + (size_t)(i0 + sr) * K + sc;
    const ushort_t* gW = W + (size_t)(j0 + sr) * K + sc;

    f32x4 acc[2][2] = {};

    for (int k0 = 0; k0 < K; k0 += BK) {
        *(us8*)&As[sr * LDP + sc] = *(const us8*)(gA + k0);
        *(us8*)&Ws[sr * LDP + sc] = *(const us8*)(gW + k0);
        __syncthreads();
        bf16x8 af[2], bfr[2];
        af[0]  = *(const bf16x8*)&As[(wm      + l15) * LDP + quad * 8];
        af[1]  = *(const bf16x8*)&As[(wm + 16 + l15) * LDP + quad * 8];
        bfr[0] = *(const bf16x8*)&Ws[(wn      + l15) * LDP + quad * 8];
        bfr[1] = *(const bf16x8*)&Ws[(wn + 16 + l15) * LDP + quad * 8];
        #pragma unroll
        for (int t = 0; t < 2; ++t)
            #pragma unroll
            for (int u = 0; u < 2; ++u)
                acc[t][u] = __builtin_amdgcn_mfma_f32_16x16x32_bf16(af[t], bfr[u], acc[t][u], 0, 0, 0);
        __syncthreads();
    }

    #pragma unroll
    for (int u = 0; u < 2; ++u) {
        const int col = j0 + wn + u * 16 + l15;
        const float bv = bias[col];
        #pragma unroll
        for (int t = 0; t < 2; ++t) {
            #pragma unroll
            for (int r = 0; r < 4; ++r) {
                const int row = i0 + wm + t * 16 + quad * 4 + r;
                float v = acc[t][u][r] + bv;
                if constexpr (RES) v += res[(size_t)row * D_MODEL + col];
                if constexpr (std::is_same<OutT, float>::value)
                    Y[(size_t)row * D_MODEL + col] = v;
                else
                    Y[(size_t)row * D_MODEL + col] = f2bf(v);
            }
        }
    }
}

// ---------------------------------------------------------------------------
// Flash attention (causal). Block = (q-tile of 64, b*H+h). 4 waves, each wave
// owns 16 queries. K-tiles of 64 keys. Q/K frags straight from global (L2),
// V staged transposed in LDS, P through LDS (C-layout -> A-layout).
// ---------------------------------------------------------------------------
__global__ __launch_bounds__(256) void attn_kernel(
    const ushort_t* __restrict__ Qg, const ushort_t* __restrict__ Kg,
    const ushort_t* __restrict__ Vg, ushort_t* __restrict__ Og)
{
    constexpr int VP = 72;                 // padded key-pitch
    __shared__ ushort_t Vt[DHEAD * VP];    // [d][key]  (V transposed)
    __shared__ ushort_t Pw[64 * VP];       // [w*16 + qrow][key]

    const int bh = blockIdx.y;
    const int b = bh >> 4;
    const int h = bh & 15;
    const int q0 = blockIdx.x * 64;
    const int tid  = threadIdx.x;
    const int lane = tid & 63;
    const int w    = tid >> 6;
    const int l15  = lane & 15;
    const int quad = lane >> 4;

    const size_t headoff = (size_t)h * DHEAD;

    const size_t qrow = (size_t)(b * SEQ + q0 + w * 16 + l15) * D_MODEL + headoff;
    const bf16x8 qf0 = *(const bf16x8*)&Qg[qrow + quad * 8];
    const bf16x8 qf1 = *(const bf16x8*)&Qg[qrow + 32 + quad * 8];

    float m_run[4] = {-1e30f, -1e30f, -1e30f, -1e30f};
    float l_run[4] = {0.f, 0.f, 0.f, 0.f};
    f32x4 o[4] = {};   // 4 n-tiles over dh=64

    const int nkt = blockIdx.x + 1;
    for (int kt = 0; kt < nkt; ++kt) {
        // stage V^T: consecutive lanes -> consecutive keys
        #pragma unroll
        for (int cc = 0; cc < 2; ++cc) {
            const int c   = tid + cc * 256;
            const int key = c & 63;
            const int dc  = c >> 6;   // 0..7
            const us8 vv = *(const us8*)&Vg[(size_t)(b * SEQ + kt * 64 + key) * D_MODEL + headoff + dc * 8];
            #pragma unroll
            for (int j = 0; j < 8; ++j)
                Vt[(dc * 8 + j) * VP + key] = vv[j];
        }
        __syncthreads();

        // S = Q K^T : 16 queries x 64 keys per wave
        f32x4 sv[4];
        #pragma unroll
        for (int f = 0; f < 4; ++f) {
            const size_t krow = (size_t)(b * SEQ + kt * 64 + f * 16 + l15) * D_MODEL + headoff;
            const bf16x8 kf0 = *(const bf16x8*)&Kg[krow + quad * 8];
            const bf16x8 kf1 = *(const bf16x8*)&Kg[krow + 32 + quad * 8];
            f32x4 s = {};
            s = __builtin_amdgcn_mfma_f32_16x16x32_bf16(qf0, kf0, s, 0, 0, 0);
            s = __builtin_amdgcn_mfma_f32_16x16x32_bf16(qf1, kf1, s, 0, 0, 0);
            sv[f] = s;
        }

        // scale + causal mask
        #pragma unroll
        for (int f = 0; f < 4; ++f) {
            const int kg = kt * 64 + f * 16 + l15;
            #pragma unroll
            for (int r = 0; r < 4; ++r) {
                const int qg = q0 + w * 16 + quad * 4 + r;
                const float s = sv[f][r] * 0.125f;
                sv[f][r] = (kg <= qg) ? s : -1e30f;
            }
        }

        // online softmax per query-row (16 lanes sharing quad hold one row)
        #pragma unroll
        for (int r = 0; r < 4; ++r) {
            float mx = fmaxf(fmaxf(sv[0][r], sv[1][r]), fmaxf(sv[2][r], sv[3][r]));
            #pragma unroll
            for (int d = 8; d >= 1; d >>= 1) mx = fmaxf(mx, __shfl_xor(mx, d));
            const float mn = fmaxf(m_run[r], mx);
            const float al = __expf(fminf(m_run[r] - mn, 0.f));
            m_run[r] = mn;
            float rs = 0.f;
            #pragma unroll
            for (int f = 0; f < 4; ++f) {
                const float p = __expf(fminf(sv[f][r] - mn, 0.f));
                sv[f][r] = p;
                rs += p;
            }
            #pragma unroll
            for (int d = 8; d >= 1; d >>= 1) rs += __shfl_xor(rs, d);
            l_run[r] = l_run[r] * al + rs;
            #pragma unroll
            for (int t = 0; t < 4; ++t) o[t][r] *= al;
        }

        // P (C-layout regs) -> LDS (row-major) for A-operand reads
        #pragma unroll
        for (int f = 0; f < 4; ++f)
            #pragma unroll
            for (int r = 0; r < 4; ++r)
                Pw[(w * 16 + quad * 4 + r) * VP + f * 16 + l15] = f2bf(sv[f][r]);

        __syncthreads();   // make P-store -> P-load ordering explicit

        // O += P V
        #pragma unroll
        for (int s = 0; s < 2; ++s) {
            const bf16x8 pf = *(const bf16x8*)&Pw[(w * 16 + l15) * VP + s * 32 + quad * 8];
            #pragma unroll
            for (int t = 0; t < 4; ++t) {
                const bf16x8 vf = *(const bf16x8*)&Vt[(t * 16 + l15) * VP + s * 32 + quad * 8];
                o[t] = __builtin_amdgcn_mfma_f32_16x16x32_bf16(pf, vf, o[t], 0, 0, 0);
            }
        }
        __syncthreads();
    }

    #pragma unroll
    for (int r = 0; r < 4; ++r) {
        const float inv = 1.f / l_run[r];
        const size_t row = (size_t)(b * SEQ + q0 + w * 16 + quad * 4 + r) * D_MODEL + headoff;
        #pragma unroll
        for (int t = 0; t < 4; ++t)
            Og[row + t * 16 + l15] = f2bf(o[t][r] * inv);
    }
}

// ---------------------------------------------------------------------------
// LayerNorm over last dim (1024), one block per row, fp32 in/out (in-place ok).
// ---------------------------------------------------------------------------
__global__ __launch_bounds__(256) void ln_kernel(
    const float* __restrict__ X, const float* __restrict__ g,
    const float* __restrict__ bta, float* __restrict__ out)
{
    __shared__ float r1[4], r2[4];
    const int row = blockIdx.x;
    const int tid = threadIdx.x;
    const float* p = X + (size_t)row * D_MODEL;
    float v[4]; float s1 = 0.f, s2 = 0.f;
    #pragma unroll
    for (int i = 0; i < 4; ++i) { v[i] = p[tid + 256 * i]; s1 += v[i]; s2 += v[i] * v[i]; }
    #pragma unroll
    for (int d = 32; d >= 1; d >>= 1) { s1 += __shfl_xor(s1, d); s2 += __shfl_xor(s2, d); }
    if ((tid & 63) == 0) { r1[tid >> 6] = s1; r2[tid >> 6] = s2; }
    __syncthreads();
    s1 = r1[0] + r1[1] + r1[2] + r1[3];
    s2 = r2[0] + r2[1] + r2[2] + r2[3];
    const float mu  = s1 * (1.f / D_MODEL);
    const float var = s2 * (1.f / D_MODEL) - mu * mu;
    const float rstd = rsqrtf(var + 1e-5f);
    #pragma unroll
    for (int i = 0; i < 4; ++i) {
        const int c = tid + 256 * i;
        out[(size_t)row * D_MODEL + c] = (v[i] - mu) * rstd * g[c] + bta[c];
    }
}

extern "C" void kernel_launch(void* const* d_in, const int* in_sizes, int n_in,
                              void* d_out, int out_size, void* d_ws, size_t ws_size,
                              hipStream_t stream) {
    const float* x     = (const float*)d_in[0];
    const float* Wq    = (const float*)d_in[1];
    const float* bq    = (const float*)d_in[2];
    const float* Wk    = (const float*)d_in[3];
    const float* bk    = (const float*)d_in[4];
    const float* Wv    = (const float*)d_in[5];
    const float* bv    = (const float*)d_in[6];
    const float* Wo    = (const float*)d_in[7];
    const float* bo    = (const float*)d_in[8];
    const float* gamma = (const float*)d_in[9];
    const float* beta  = (const float*)d_in[10];

    const size_t XN = (size_t)MROWS * D_MODEL;      // 4 Mi elements
    const size_t WN = (size_t)D_MODEL * D_MODEL;    // 1 Mi elements
    // ws layout (bf16 units), 40 MiB total:
    //   [0,4M)   xb  (dead after QKV gemm) -> reused as ctx during attention
    //   [4M,8M)  Yq   [8M,12M) Yk   [12M,16M) Yv
    //   [16M,20M) Wqb,Wkb,Wvb,Wob (1M each)
    ushort_t* wsp = (ushort_t*)d_ws;
    ushort_t* xb  = wsp;
    ushort_t* Yq  = wsp + XN;
    ushort_t* Yk  = wsp + 2 * XN;
    ushort_t* Yv  = wsp + 3 * XN;
    ushort_t* Wqb = wsp + 4 * XN;
    ushort_t* Wkb = Wqb + WN;
    ushort_t* Wvb = Wkb + WN;
    ushort_t* Wob = Wvb + WN;
    ushort_t* ctx = xb;                 // overlay: xb dead after QKV gemm
    float*    pre = (float*)d_out;      // fp32 pre-LN lives in d_out; LN in-place

    // fp32 -> bf16 canonicalization (8M elements, 4/thread)
    cvt_kernel<<<dim3(8192), 256, 0, stream>>>(x, Wq, Wk, Wv, Wo, xb, Wqb, Wkb, Wvb, Wob);

    // QKV projections (fused as grid.z = 3)
    gemm_nt<ushort_t, false><<<dim3(MROWS / 64, D_MODEL / 64, 3), 256, 0, stream>>>(
        xb, Wqb, Wkb, Wvb, bq, bk, bv, nullptr, Yq, Yk, Yv);

    // causal flash attention
    attn_kernel<<<dim3(SEQ / 64, BATCH * NHEADS), 256, 0, stream>>>(Yq, Yk, Yv, ctx);

    // output projection + bias + residual(x, fp32) -> fp32 pre-LN in d_out
    gemm_nt<float, true><<<dim3(MROWS / 64, D_MODEL / 64, 1), 256, 0, stream>>>(
        ctx, Wob, Wob, Wob, bo, bo, bo, x, pre, pre, pre);

    // LayerNorm in-place on d_out
    ln_kernel<<<dim3(MROWS), 256, 0, stream>>>(pre, gamma, beta, (float*)d_out);
}